// Round 13
// baseline (224.493 us; speedup 1.0000x reference)
//
#include <hip/hip_runtime.h>
#include <hip/hip_bf16.h>
#include <math.h>

#define DEV __device__ __forceinline__

DEV float gelu_exact(float x){ return 0.5f*x*(1.0f + erff(x*0.70710678118654752f)); }

// ---------------- K1: conv1(1->16,3x3,pad1) + maxpool2 + gelu  (+ fused weight prep) ----------------
__global__ __launch_bounds__(256) void k_conv1(const float* __restrict__ x,
    const float* __restrict__ w1, const float* __restrict__ b1,
    float* __restrict__ h1,
    const float* __restrict__ w2, const float* __restrict__ d2,
    float* __restrict__ w2t, float* __restrict__ wp4d2)
{
  __shared__ float sE[34*19], sO[34*19];
  const int b = blockIdx.z;
  const int r0 = blockIdx.x*32, c0 = blockIdx.y*32;
  const float* xp = x + (size_t)b*65536;
  for(int i=threadIdx.x;i<34*34;i+=256){
    int r=i/34, c=i-r*34;
    int gr=r0+r-1, gc=c0+c-1;
    float v=0.f;
    if(gr>=0 && gr<256 && gc>=0 && gc<256) v = xp[gr*256+gc];
    if(c&1) sO[r*19+(c>>1)]=v; else sE[r*19+(c>>1)]=v;
  }
  __syncthreads();
  const int tx=threadIdx.x&15, ty=threadIdx.x>>4;
  const int base = 2*ty*19 + tx;
  float in[4][4];
  #pragma unroll
  for(int r=0;r<4;r++){
    in[r][0]=sE[base+r*19]; in[r][1]=sO[base+r*19];
    in[r][2]=sE[base+r*19+1]; in[r][3]=sO[base+r*19+1];
  }
  const int py = blockIdx.x*16+ty, px = blockIdx.y*16+tx;
  float* op = h1 + ((size_t)b*16)*16384 + py*128 + px;
  #pragma unroll
  for(int ch=0;ch<16;ch++){
    float m=-1e30f;
    #pragma unroll
    for(int pr=0;pr<2;pr++)
      #pragma unroll
      for(int pc=0;pc<2;pc++){
        float a=0.f;
        #pragma unroll
        for(int ky=0;ky<3;ky++)
          #pragma unroll
          for(int kx=0;kx<3;kx++)
            a = fmaf(in[pr+ky][pc+kx], w1[ch*9+ky*3+kx], a);
        m = fmaxf(m,a);
      }
    op[(size_t)ch*16384] = gelu_exact(m + b1[ch]);
  }
  // ---- fused prep (8 blocks worth of work) ----
  if(blockIdx.x==0 && blockIdx.y==0 && b<8){
    const int gid = b*256 + threadIdx.x;
    for(int i=gid;i<4608;i+=2048){           // w2 (oc,ic,k) -> w2t[(ic*32+oc)*9+k]
      int oc=i/144, rem=i-oc*144, ic=rem/9, k=rem-ic*9;
      w2t[(ic*32+oc)*9+k]=w2[i];
    }
    for(int i=gid;i<2048;i+=2048){           // d2 parity-combined float4 table
      int par=i>>9, ic=(i>>4)&31, oc=i&15;
      int pyp=par>>1, pxp=par&1;
      const float* wg = d2 + ((size_t)oc*32+ic)*9;
      float a00=0.f,a01=0.f,a10=0.f,a11=0.f;
      #pragma unroll
      for(int ky=0;ky<3;ky++){
        int sy = pyp ? (ky>>1) : ((ky>0)?1:0);
        #pragma unroll
        for(int kx=0;kx<3;kx++){
          int sx = pxp ? (kx>>1) : ((kx>0)?1:0);
          float wv=wg[ky*3+kx];
          if(sy==0){ if(sx==0)a00+=wv; else a01+=wv; }
          else     { if(sx==0)a10+=wv; else a11+=wv; }
        }
      }
      float* dst=wp4d2+(size_t)i*4;
      dst[0]=a00; dst[1]=a01; dst[2]=a10; dst[3]=a11;
    }
  }
}

// ---------------- K2: conv2(16->32,3x3,pad1) + maxpool2 + groupnorm partials ----------------
__global__ __launch_bounds__(256) void k_conv2(const float* __restrict__ h1,
    const float* __restrict__ w2t, const float* __restrict__ b2,
    float* __restrict__ h2, double* __restrict__ pb)
{
  __shared__ __align__(16) float t2[2][8*360];   // [buf][ic][18][20]
  const int b=blockIdx.z;
  const int r0=blockIdx.x*16, c0=blockIdx.y*16;  // unpooled origin (128-res)
  const float* hp = h1 + (size_t)b*16*16384;
  const int t=threadIdx.x;
  int lofs[6]; int gof[6]; bool ok0[6], ok1[6];
  #pragma unroll
  for(int s=0;s<6;s++){
    int idx=s*256+t;
    int ic=idx/162, rem=idx-162*ic, lr=rem/9, jp=rem-9*lr;
    int gr=r0+lr-1, gc=c0+2*jp-1;
    bool rok = (gr>=0) && (gr<128);
    ok0[s] = rok && (gc>=0);
    ok1[s] = rok && (gc+1<128);
    lofs[s]= ic*360+lr*20+2*jp;
    gof[s] = ic*16384 + gr*128 + gc;
  }
  float a0[6], a1[6], c0r[6], c1r[6];
  #pragma unroll
  for(int s=0;s<6;s++){
    if(s<5 || t<16){
      a0[s] = ok0[s] ? hp[gof[s]]   : 0.f;
      a1[s] = ok1[s] ? hp[gof[s]+1] : 0.f;
    }
  }
  #pragma unroll
  for(int s=0;s<6;s++)
    if(s<5 || t<16) *(float2*)&t2[0][lofs[s]]=make_float2(a0[s],a1[s]);
  const float* hp1 = hp + 8*16384;
  #pragma unroll
  for(int s=0;s<6;s++){
    if(s<5 || t<16){
      c0r[s] = ok0[s] ? hp1[gof[s]]   : 0.f;
      c1r[s] = ok1[s] ? hp1[gof[s]+1] : 0.f;
    }
  }
  __syncthreads();

  const int pos=t&63;
  const int ocg=__builtin_amdgcn_readfirstlane((int)(t>>6));
  const int oc0=ocg*8;
  const int pyl=pos>>3, pxl=pos&7;
  const int base0 = 2*pyl*20 + 2*pxl;
  float acc[8][4];
  #pragma unroll
  for(int o=0;o<8;o++)
    #pragma unroll
    for(int j=0;j<4;j++) acc[o][j]=0.f;

  #pragma unroll 4
  for(int ic=0;ic<8;ic++){
    float in[4][4];
    #pragma unroll
    for(int r=0;r<4;r++){
      float2 a=*(const float2*)&t2[0][ic*360 + base0 + r*20];
      float2 c=*(const float2*)&t2[0][ic*360 + base0 + r*20 + 2];
      in[r][0]=a.x; in[r][1]=a.y; in[r][2]=c.x; in[r][3]=c.y;
    }
    const float* wp = w2t + (ic*32+oc0)*9;
    #pragma unroll
    for(int o=0;o<8;o++){
      #pragma unroll
      for(int pr=0;pr<2;pr++)
        #pragma unroll
        for(int pc=0;pc<2;pc++){
          float s=acc[o][pr*2+pc];
          #pragma unroll
          for(int ky=0;ky<3;ky++)
            #pragma unroll
            for(int kx=0;kx<3;kx++)
              s=fmaf(in[pr+ky][pc+kx], wp[o*9+ky*3+kx], s);
          acc[o][pr*2+pc]=s;
        }
    }
  }
  #pragma unroll
  for(int s=0;s<6;s++)
    if(s<5 || t<16) *(float2*)&t2[1][lofs[s]]=make_float2(c0r[s],c1r[s]);
  __syncthreads();
  #pragma unroll 4
  for(int ic=0;ic<8;ic++){
    float in[4][4];
    #pragma unroll
    for(int r=0;r<4;r++){
      float2 a=*(const float2*)&t2[1][ic*360 + base0 + r*20];
      float2 c=*(const float2*)&t2[1][ic*360 + base0 + r*20 + 2];
      in[r][0]=a.x; in[r][1]=a.y; in[r][2]=c.x; in[r][3]=c.y;
    }
    const float* wp = w2t + ((8+ic)*32+oc0)*9;
    #pragma unroll
    for(int o=0;o<8;o++){
      #pragma unroll
      for(int pr=0;pr<2;pr++)
        #pragma unroll
        for(int pc=0;pc<2;pc++){
          float s=acc[o][pr*2+pc];
          #pragma unroll
          for(int ky=0;ky<3;ky++)
            #pragma unroll
            for(int kx=0;kx<3;kx++)
              s=fmaf(in[pr+ky][pc+kx], wp[o*9+ky*3+kx], s);
          acc[o][pr*2+pc]=s;
        }
    }
  }

  const int py=blockIdx.x*8+pyl, px=blockIdx.y*8+pxl;
  double s=0.0, s2=0.0;
  #pragma unroll
  for(int o=0;o<8;o++){
    const int oc=oc0+o;
    float m=fmaxf(fmaxf(acc[o][0],acc[o][1]),fmaxf(acc[o][2],acc[o][3]));
    float hv=m+b2[oc];
    h2[(((size_t)b*32+oc)*64+py)*64+px]=hv;
    s += (double)hv; s2 += (double)hv*(double)hv;
  }
  #pragma unroll
  for(int off=32;off;off>>=1){
    s  += __shfl_xor(s,  off, 64);
    s2 += __shfl_xor(s2, off, 64);
  }
  if(pos==0){
    const int bidx = blockIdx.x*8 + blockIdx.y;
    double* p = pb + (((size_t)b*4+ocg)*64 + bidx)*2;
    p[0]=s; p[1]=s2;
  }
}

// ---------------- K3: groupnorm stats (fused) + apply + 1x1 conv + residual LFQ ----------------
__global__ __launch_bounds__(256) void k_lfq(const float* __restrict__ h2,
    const double* __restrict__ pb, const float* __restrict__ w3, const float* __restrict__ b3,
    float* __restrict__ qout, float* __restrict__ idxout,
    float* __restrict__ avgp, float* __restrict__ ec)
{
  __shared__ __align__(16) float tabL[16*260];
  __shared__ __align__(16) float tabH[16*260];
  __shared__ float smu[4], srs[4];
  const int blk=blockIdx.x;
  const int b=blk>>4;
  const int t=threadIdx.x;
  const int h=(blk&15)*4 + (t>>6);
  const int w=t&63;
  {
    const int wv=t>>6, ln=t&63;
    double s = pb[(((size_t)b*4+wv)*64+ln)*2];
    double s2= pb[(((size_t)b*4+wv)*64+ln)*2+1];
    #pragma unroll
    for(int off=32;off;off>>=1){
      s  += __shfl_xor(s,  off, 64);
      s2 += __shfl_xor(s2, off, 64);
    }
    if(ln==0){
      double mu=s/32768.0;
      double var=s2/32768.0 - mu*mu;
      smu[wv]=(float)mu;
      srs[wv]=(float)(1.0/sqrt(var+1e-5));
    }
  }
  __syncthreads();
  float mu[4], rs[4];
  #pragma unroll
  for(int g=0;g<4;g++){ mu[g]=smu[g]; rs[g]=srs[g]; }
  const float* hp = h2 + (size_t)b*131072 + h*64 + w;
  float z[8];
  #pragma unroll
  for(int d=0;d<8;d++) z[d]=b3[d];
  #pragma unroll
  for(int c=0;c<32;c++){
    float xn=(hp[(size_t)c*4096]-mu[c>>3])*rs[c>>3];
    #pragma unroll
    for(int d=0;d<8;d++) z[d]=fmaf(xn, w3[d*32+c], z[d]);
  }
  float r[8], qsum[8];
  #pragma unroll
  for(int d=0;d<8;d++){ r[d]=z[d]; qsum[d]=0.f; }
  float entk[2], comk[2];
  #pragma unroll
  for(int k=0;k<2;k++){
    int idx=0; float ent=0.f, com=0.f;
    float pb0[8], pb1[8];
    #pragma unroll
    for(int d=0;d<8;d++){
      float rv=r[d];
      bool pos = rv>0.f;
      float sgn = pos?1.f:-1.f;
      idx |= (pos?1:0)<<d;
      float dd=rv-sgn; com=fmaf(dd,dd,com);
      float a=400.f*fabsf(rv);
      float e=__expf(-a);
      float p=1.f/(1.f+e);
      ent += a - p*a - __logf(p);
      float pm=p, pq=1.f-p;
      pb1[d]=pos?pm:pq;
      pb0[d]=pos?pq:pm;
      qsum[d]+=sgn;
      r[d]=rv-sgn;
    }
    float lo[16], hi[16];
    lo[0]=pb0[0]; lo[1]=pb1[0];
    lo[2]=lo[0]*pb1[1]; lo[3]=lo[1]*pb1[1]; lo[0]*=pb0[1]; lo[1]*=pb0[1];
    lo[4]=lo[0]*pb1[2]; lo[5]=lo[1]*pb1[2]; lo[6]=lo[2]*pb1[2]; lo[7]=lo[3]*pb1[2];
    lo[0]*=pb0[2]; lo[1]*=pb0[2]; lo[2]*=pb0[2]; lo[3]*=pb0[2];
    lo[8]=lo[0]*pb1[3]; lo[9]=lo[1]*pb1[3]; lo[10]=lo[2]*pb1[3]; lo[11]=lo[3]*pb1[3];
    lo[12]=lo[4]*pb1[3]; lo[13]=lo[5]*pb1[3]; lo[14]=lo[6]*pb1[3]; lo[15]=lo[7]*pb1[3];
    lo[0]*=pb0[3]; lo[1]*=pb0[3]; lo[2]*=pb0[3]; lo[3]*=pb0[3];
    lo[4]*=pb0[3]; lo[5]*=pb0[3]; lo[6]*=pb0[3]; lo[7]*=pb0[3];
    hi[0]=pb0[4]; hi[1]=pb1[4];
    hi[2]=hi[0]*pb1[5]; hi[3]=hi[1]*pb1[5]; hi[0]*=pb0[5]; hi[1]*=pb0[5];
    hi[4]=hi[0]*pb1[6]; hi[5]=hi[1]*pb1[6]; hi[6]=hi[2]*pb1[6]; hi[7]=hi[3]*pb1[6];
    hi[0]*=pb0[6]; hi[1]*=pb0[6]; hi[2]*=pb0[6]; hi[3]*=pb0[6];
    hi[8]=hi[0]*pb1[7]; hi[9]=hi[1]*pb1[7]; hi[10]=hi[2]*pb1[7]; hi[11]=hi[3]*pb1[7];
    hi[12]=hi[4]*pb1[7]; hi[13]=hi[5]*pb1[7]; hi[14]=hi[6]*pb1[7]; hi[15]=hi[7]*pb1[7];
    hi[0]*=pb0[7]; hi[1]*=pb0[7]; hi[2]*=pb0[7]; hi[3]*=pb0[7];
    hi[4]*=pb0[7]; hi[5]*=pb0[7]; hi[6]*=pb0[7]; hi[7]*=pb0[7];
    #pragma unroll
    for(int m=0;m<16;m++){ tabL[m*260+t]=lo[m]; tabH[m*260+t]=hi[m]; }
    __syncthreads();
    float accp=0.f, accq=0.f;
    const int jl=t&15, jh=t>>4;
    const float* Lp=&tabL[jl*260];
    const float* Hp=&tabH[jh*260];
    #pragma unroll 4
    for(int q4=0;q4<64;q4++){
      float4 L=*(const float4*)&Lp[4*q4];
      float4 H=*(const float4*)&Hp[4*q4];
      accp=fmaf(L.x,H.x,accp); accq=fmaf(L.y,H.y,accq);
      accp=fmaf(L.z,H.z,accp); accq=fmaf(L.w,H.w,accq);
    }
    avgp[((size_t)k*512+blk)*256+t]=accp+accq;
    __syncthreads();
    entk[k]=ent; comk[k]=com;
    idxout[((size_t)(b*64+h)*64+w)*2+k]=(float)idx;
  }
  #pragma unroll
  for(int d=0;d<8;d++)
    qout[(((size_t)b*8+d)*64+h)*64+w]=qsum[d];
  tabL[t]=entk[0]; tabL[256+t]=entk[1]; tabL[512+t]=comk[0]; tabL[768+t]=comk[1];
  __syncthreads();
  for(int st=128;st>0;st>>=1){
    if(t<st){ tabL[t]+=tabL[t+st]; tabL[256+t]+=tabL[256+t+st];
              tabL[512+t]+=tabL[512+t+st]; tabL[768+t]+=tabL[768+t+st]; }
    __syncthreads();
  }
  if(t==0){ ec[blk*4+0]=tabL[0]; ec[blk*4+1]=tabL[256]; ec[blk*4+2]=tabL[512]; ec[blk*4+3]=tabL[768]; }
}

// ---------------- K4: FUSED decoder (dec1 -> dec2 -> dec3 in LDS) + avgp-red piggyback ------------
// grid (8,8,32) block 256; y tile 32x32 at 256-res.
// LDS chain: qs[8][12][13] (aliases o2) -> o1[32][10][11] -> o2[16][18][19] -> y.
// Boundary semantics identical to the verified split kernels (zero tiles outside range).
__global__ __launch_bounds__(256) void k_dec(const float* __restrict__ q,
    const float* __restrict__ d1, const float* __restrict__ db1,
    const float* __restrict__ wp4d2, const float* __restrict__ db2,
    const float* __restrict__ d3, const float* __restrict__ db3,
    float* __restrict__ y,
    const float* __restrict__ avgp, float* __restrict__ avgs)
{
  __shared__ float o1[32*110];      // [oc1][10][11]
  __shared__ float o2[16*342];      // [oc2][18][19]; head aliases qs [8][12 rows][13 stride]
  __shared__ float4 wp4[64];        // d3 parity table [par*16+ic]
  __shared__ float red[256];
  const int b=blockIdx.z, bx=blockIdx.x, by=blockIdx.y;
  const int t=threadIdx.x;
  float* qs = o2;                   // alias: qs dead before o2 written (barrier between)

  // ---- stage q tile (64-res rows 8bx-2..+9, cols 8by-2..+9) + build d3 table ----
  const float* qp = q + (size_t)b*8*4096;
  const int qr0=8*bx-2, qc0=8*by-2;
  for(int i=t;i<1152;i+=256){       // 8*12*12
    int ic=i/144, rem=i-144*ic, r=rem/12, c=rem-12*r;
    int gr=qr0+r, gc=qc0+c;
    float v=0.f;
    if((unsigned)gr<64u && (unsigned)gc<64u) v=qp[ic*4096+gr*64+gc];
    qs[ic*156+r*13+c]=v;
  }
  if(t<64){
    int par=t>>4, ic=t&15;
    int pyp=par>>1, pxp=par&1;
    const float* wg = d3 + ic*9;
    float a00=0.f,a01=0.f,a10=0.f,a11=0.f;
    #pragma unroll
    for(int ky=0;ky<3;ky++){
      int sy = pyp ? (ky>>1) : ((ky>0)?1:0);
      #pragma unroll
      for(int kx=0;kx<3;kx++){
        int sx = pxp ? (kx>>1) : ((kx>0)?1:0);
        float wv=wg[ky*3+kx];
        if(sy==0){ if(sx==0)a00+=wv; else a01+=wv; }
        else     { if(sx==0)a10+=wv; else a11+=wv; }
      }
    }
    wp4[t]=make_float4(a00,a01,a10,a11);
  }
  __syncthreads();

  // ---- phase 1 (dec1): o1[oc][r][c], r,c in 0..9; 64-res coords 8bx-1+r ----
  {
    const int wv=__builtin_amdgcn_readfirstlane((int)(t>>6));
    const int oc0=wv*8;
    const int l=t&63;
    #pragma unroll
    for(int s=0;s<2;s++){
      int j=l+64*s;
      if(j<100){
        int r=j/10, c=j-10*r;
        bool valid = ((unsigned)(8*bx-1+r)<64u) && ((unsigned)(8*by-1+c)<64u);
        float acc[8];
        #pragma unroll
        for(int o=0;o<8;o++) acc[o]=db1[oc0+o];
        if(valid){
          #pragma unroll 2
          for(int ic=0;ic<8;ic++){
            float v[9];
            #pragma unroll
            for(int ky=0;ky<3;ky++)
              #pragma unroll
              for(int kx=0;kx<3;kx++)
                v[ky*3+kx]=qs[ic*156+(r+ky)*13+(c+kx)];
            #pragma unroll
            for(int o=0;o<8;o++){
              const float* wp=&d1[((oc0+o)*8+ic)*9];
              float ss=acc[o];
              #pragma unroll
              for(int kk=0;kk<9;kk++) ss=fmaf(v[kk],wp[kk],ss);
              acc[o]=ss;
            }
          }
        }
        #pragma unroll
        for(int o=0;o<8;o++)
          o1[(oc0+o)*110 + r*11 + c] = valid ? acc[o] : 0.f;
      }
    }
  }
  __syncthreads();

  // ---- phase 2 (dec2): o2[oc2][rr][cc], rr,cc in 0..17; 128-res gy=16bx-1+rr ----
  // parity-quadrant organization: par uniform per sub-loop -> scalar weights.
  {
    const int wv=__builtin_amdgcn_readfirstlane((int)(t>>6));
    const int ocb=wv*4;
    const int l=t&63;
    #pragma unroll
    for(int par4=0;par4<4;par4++){
      const int qr=par4>>1, qc=par4&1;
      const int par=((qr^1)<<1)|(qc^1);
      const float* wqb = wp4d2 + (size_t)(par*512)*4;
      #pragma unroll
      for(int s=0;s<2;s++){
        int j=l+64*s;
        if(j<81){
          int rq=j/9, cq=j-9*rq;
          int rr=2*rq+qr, cc=2*cq+qc;
          bool valid = ((unsigned)(16*bx-1+rr)<128u)&&((unsigned)(16*by-1+cc)<128u);
          float acc[4];
          #pragma unroll
          for(int o=0;o<4;o++) acc[o]=db2[ocb+o];
          #pragma unroll 4
          for(int ic=0;ic<32;ic++){
            const float* tp=&o1[ic*110 + rq*11 + cq];
            float s00=tp[0], s01=tp[1], s10=tp[11], s11=tp[12];
            const float* wq = wqb + (ic*16+ocb)*4;
            #pragma unroll
            for(int o=0;o<4;o++)
              acc[o]=fmaf(s00,wq[o*4],fmaf(s01,wq[o*4+1],fmaf(s10,wq[o*4+2],fmaf(s11,wq[o*4+3],acc[o]))));
          }
          #pragma unroll
          for(int o=0;o<4;o++)
            o2[(ocb+o)*342 + rr*19 + cc] = valid ? gelu_exact(acc[o]) : 0.f;
        }
      }
    }
  }
  __syncthreads();

  // ---- phase 3 (dec3): y 32x32 from o2 (verified dec3 lane mapping) ----
  {
    const float bias=db3[0];
    const int par=__builtin_amdgcn_readfirstlane((int)(t>>6));
    const int py=par>>1, px=par&1;
    const int l=t&63, r0l=l>>4, cl=l&15;
    const int bxl=cl+px;
    float acc[4];
    #pragma unroll
    for(int a=0;a<4;a++) acc[a]=bias;
    #pragma unroll 2
    for(int ic=0;ic<16;ic++){
      const float4 wv4=wp4[par*16+ic];
      #pragma unroll
      for(int a=0;a<4;a++){
        const int byl=r0l+4*a+py;
        const float* tp=&o2[ic*342 + byl*19 + bxl];
        acc[a]=fmaf(tp[0],wv4.x,fmaf(tp[1],wv4.y,fmaf(tp[19],wv4.z,fmaf(tp[20],wv4.w,acc[a]))));
      }
    }
    const int y0=bx*32, x0=by*32;
    #pragma unroll
    for(int a=0;a<4;a++){
      const int yy=2*(r0l+4*a)+py, xx=2*cl+px;
      float v=fminf(fmaxf(acc[a],-1.0f),1.0f);
      y[(size_t)b*65536 + (size_t)(y0+yy)*256 + (x0+xx)] = v;
    }
  }

  // ---- piggybacked avgp reduction (32 designated blocks) ----
  if(bx==0 && b<4){
    const int rid = b*8 + by;          // 0..31
    const int k=rid>>4, cc0=(rid&15)*16;
    const int col=t&15, rg=t>>4;
    float s=0.f;
    for(int j=0;j<32;j++){
      int blk=rg+16*j;
      s+=avgp[((size_t)k*512+blk)*256+cc0+col];
    }
    red[t]=s; __syncthreads();
    for(int st=128;st>=16;st>>=1){
      if(t<st) red[t]+=red[t+st];
      __syncthreads();
    }
    if(t<16) avgs[k*256+cc0+t]=red[t];
  }
}

// ---------------- K5: final aux (1 block, tiny reads, f64 deterministic) ----------------
__global__ __launch_bounds__(256) void k_final(const float* __restrict__ avgs,
    const float* __restrict__ ec, float* __restrict__ auxout)
{
  __shared__ double red[256];
  const int t=threadIdx.x;
  double cb=0.0;
  #pragma unroll
  for(int k=0;k<2;k++){
    double ap=(double)avgs[k*256+t]*(1.0/131072.0);
    cb += -(ap*log(ap+1e-10));
  }
  red[t]=cb; __syncthreads();
  for(int st=128;st>0;st>>=1){ if(t<st) red[t]+=red[t+st]; __syncthreads(); }
  double CB=red[0]; __syncthreads();
  double e=0.0,c=0.0;
  for(int blk=t;blk<512;blk+=256){
    e += (double)ec[blk*4+0]+(double)ec[blk*4+1];
    c += (double)ec[blk*4+2]+(double)ec[blk*4+3];
  }
  red[t]=e; __syncthreads();
  for(int st=128;st>0;st>>=1){ if(t<st) red[t]+=red[t+st]; __syncthreads(); }
  double E=red[0]; __syncthreads();
  red[t]=c; __syncthreads();
  for(int st=128;st>0;st>>=1){ if(t<st) red[t]+=red[t+st]; __syncthreads(); }
  if(t==0){
    double C=red[0];
    double aux = 0.1*(E*(1.0/131072.0) - CB) + C*(1.0/1048576.0);
    auxout[0]=(float)aux;
  }
}

extern "C" void kernel_launch(void* const* d_in, const int* in_sizes, int n_in,
                              void* d_out, int out_size, void* d_ws, size_t ws_size,
                              hipStream_t stream)
{
  const float* x  =(const float*)d_in[0];
  const float* w1 =(const float*)d_in[1];
  const float* b1 =(const float*)d_in[2];
  const float* w2 =(const float*)d_in[3];
  const float* b2 =(const float*)d_in[4];
  const float* w3 =(const float*)d_in[5];
  const float* b3 =(const float*)d_in[6];
  const float* d1 =(const float*)d_in[7];
  const float* db1=(const float*)d_in[8];
  const float* d2 =(const float*)d_in[9];
  const float* db2=(const float*)d_in[10];
  const float* d3 =(const float*)d_in[11];
  const float* db3=(const float*)d_in[12];
  float* out=(float*)d_out;
  float* ws =(float*)d_ws;
  // ws layout (floats):
  // h1[8388608] | h2[4194304] | qb[1048576] | (gap) | avgp[262144] | ec[2048]
  // | wp4d2[8192] | avgs[512]
  // Aliases (stream-order disjoint):
  //   w2t (4608 fl) = head of avgp  (conv1-prep -> conv2, then lfq overwrites avgp)
  // d_out scratch (y region, fully overwritten by k_dec):
  //   pb (16384 f64 = 32768 fl) @ out+0  (conv2 -> lfq; dead before k_dec writes y)
  float* h1   = ws;
  float* h2   = ws + 8388608;
  float* qb   = ws + 12582912;
  float* avgp = ws + 13631744;
  float* ec   = ws + 13893888;
  float* wp4d2= ws + 13895936;
  float* avgs = ws + 13904128;
  float* w2t  = avgp;
  double* pb  = (double*)out;

  k_conv1<<<dim3(8,8,32),256,0,stream>>>(x,w1,b1,h1,w2,d2,w2t,wp4d2);
  k_conv2<<<dim3(8,8,32),256,0,stream>>>(h1,w2t,b2,h2,pb);
  k_lfq  <<<dim3(512),256,0,stream>>>(h2,pb,w3,b3,qb,out+2097152,avgp,ec);
  k_dec  <<<dim3(8,8,32),256,0,stream>>>(qb,d1,db1,wp4d2,db2,d3,db3,out,avgp,avgs);
  k_final<<<dim3(1),256,0,stream>>>(avgs,ec,out+2359296);
}

// Round 14
// 188.265 us; speedup vs baseline: 1.1924x; 1.1924x over previous
//
#include <hip/hip_runtime.h>
#include <hip/hip_bf16.h>
#include <math.h>

#define DEV __device__ __forceinline__

DEV float gelu_exact(float x){ return 0.5f*x*(1.0f + erff(x*0.70710678118654752f)); }

// ---------------- K1: conv1(1->16,3x3,pad1) + maxpool2 + gelu  (+ fused weight prep) ----------------
__global__ __launch_bounds__(256) void k_conv1(const float* __restrict__ x,
    const float* __restrict__ w1, const float* __restrict__ b1,
    float* __restrict__ h1,
    const float* __restrict__ w2, const float* __restrict__ d2,
    float* __restrict__ w2t, float* __restrict__ wp4d2)
{
  __shared__ float sE[34*19], sO[34*19];
  const int b = blockIdx.z;
  const int r0 = blockIdx.x*32, c0 = blockIdx.y*32;
  const float* xp = x + (size_t)b*65536;
  for(int i=threadIdx.x;i<34*34;i+=256){
    int r=i/34, c=i-r*34;
    int gr=r0+r-1, gc=c0+c-1;
    float v=0.f;
    if(gr>=0 && gr<256 && gc>=0 && gc<256) v = xp[gr*256+gc];
    if(c&1) sO[r*19+(c>>1)]=v; else sE[r*19+(c>>1)]=v;
  }
  __syncthreads();
  const int tx=threadIdx.x&15, ty=threadIdx.x>>4;
  const int base = 2*ty*19 + tx;
  float in[4][4];
  #pragma unroll
  for(int r=0;r<4;r++){
    in[r][0]=sE[base+r*19]; in[r][1]=sO[base+r*19];
    in[r][2]=sE[base+r*19+1]; in[r][3]=sO[base+r*19+1];
  }
  const int py = blockIdx.x*16+ty, px = blockIdx.y*16+tx;
  float* op = h1 + ((size_t)b*16)*16384 + py*128 + px;
  #pragma unroll
  for(int ch=0;ch<16;ch++){
    float m=-1e30f;
    #pragma unroll
    for(int pr=0;pr<2;pr++)
      #pragma unroll
      for(int pc=0;pc<2;pc++){
        float a=0.f;
        #pragma unroll
        for(int ky=0;ky<3;ky++)
          #pragma unroll
          for(int kx=0;kx<3;kx++)
            a = fmaf(in[pr+ky][pc+kx], w1[ch*9+ky*3+kx], a);
        m = fmaxf(m,a);
      }
    op[(size_t)ch*16384] = gelu_exact(m + b1[ch]);
  }
  // ---- fused prep (8 blocks worth of work) ----
  if(blockIdx.x==0 && blockIdx.y==0 && b<8){
    const int gid = b*256 + threadIdx.x;
    for(int i=gid;i<4608;i+=2048){           // w2 (oc,ic,k) -> w2t[(ic*32+oc)*9+k]
      int oc=i/144, rem=i-oc*144, ic=rem/9, k=rem-ic*9;
      w2t[(ic*32+oc)*9+k]=w2[i];
    }
    for(int i=gid;i<2048;i+=2048){           // d2 parity-combined float4 table
      int par=i>>9, ic=(i>>4)&31, oc=i&15;
      int pyp=par>>1, pxp=par&1;
      const float* wg = d2 + ((size_t)oc*32+ic)*9;
      float a00=0.f,a01=0.f,a10=0.f,a11=0.f;
      #pragma unroll
      for(int ky=0;ky<3;ky++){
        int sy = pyp ? (ky>>1) : ((ky>0)?1:0);
        #pragma unroll
        for(int kx=0;kx<3;kx++){
          int sx = pxp ? (kx>>1) : ((kx>0)?1:0);
          float wv=wg[ky*3+kx];
          if(sy==0){ if(sx==0)a00+=wv; else a01+=wv; }
          else     { if(sx==0)a10+=wv; else a11+=wv; }
        }
      }
      float* dst=wp4d2+(size_t)i*4;
      dst[0]=a00; dst[1]=a01; dst[2]=a10; dst[3]=a11;
    }
  }
}

// ---------------- K2: conv2(16->32,3x3,pad1) + maxpool2 + groupnorm partials ----------------
// R7-verified: double-buffered pixel LDS, register-staged (half-1 loads issued before
// first barrier), 2 barriers/block, transposed s_load weights.
__global__ __launch_bounds__(256) void k_conv2(const float* __restrict__ h1,
    const float* __restrict__ w2t, const float* __restrict__ b2,
    float* __restrict__ h2, double* __restrict__ pb)
{
  __shared__ __align__(16) float t2[2][8*360];   // [buf][ic][18][20]
  const int b=blockIdx.z;
  const int r0=blockIdx.x*16, c0=blockIdx.y*16;  // unpooled origin (128-res)
  const float* hp = h1 + (size_t)b*16*16384;
  const int t=threadIdx.x;
  // staging descriptors (slots 0..4 full, slot 5: t<16)
  int lofs[6]; int gof[6]; bool ok0[6], ok1[6];
  #pragma unroll
  for(int s=0;s<6;s++){
    int idx=s*256+t;
    int ic=idx/162, rem=idx-162*ic, lr=rem/9, jp=rem-9*lr;
    int gr=r0+lr-1, gc=c0+2*jp-1;
    bool rok = (gr>=0) && (gr<128);
    ok0[s] = rok && (gc>=0);
    ok1[s] = rok && (gc+1<128);
    lofs[s]= ic*360+lr*20+2*jp;
    gof[s] = ic*16384 + gr*128 + gc;
  }
  float a0[6], a1[6], c0r[6], c1r[6];
  #pragma unroll
  for(int s=0;s<6;s++){
    if(s<5 || t<16){
      a0[s] = ok0[s] ? hp[gof[s]]   : 0.f;
      a1[s] = ok1[s] ? hp[gof[s]+1] : 0.f;
    }
  }
  #pragma unroll
  for(int s=0;s<6;s++)
    if(s<5 || t<16) *(float2*)&t2[0][lofs[s]]=make_float2(a0[s],a1[s]);
  const float* hp1 = hp + 8*16384;
  #pragma unroll
  for(int s=0;s<6;s++){
    if(s<5 || t<16){
      c0r[s] = ok0[s] ? hp1[gof[s]]   : 0.f;
      c1r[s] = ok1[s] ? hp1[gof[s]+1] : 0.f;
    }
  }
  __syncthreads();

  const int pos=t&63;
  const int ocg=__builtin_amdgcn_readfirstlane((int)(t>>6));
  const int oc0=ocg*8;
  const int pyl=pos>>3, pxl=pos&7;
  const int base0 = 2*pyl*20 + 2*pxl;
  float acc[8][4];
  #pragma unroll
  for(int o=0;o<8;o++)
    #pragma unroll
    for(int j=0;j<4;j++) acc[o][j]=0.f;

  // compute half 0
  #pragma unroll 4
  for(int ic=0;ic<8;ic++){
    float in[4][4];
    #pragma unroll
    for(int r=0;r<4;r++){
      float2 a=*(const float2*)&t2[0][ic*360 + base0 + r*20];
      float2 c=*(const float2*)&t2[0][ic*360 + base0 + r*20 + 2];
      in[r][0]=a.x; in[r][1]=a.y; in[r][2]=c.x; in[r][3]=c.y;
    }
    const float* wp = w2t + (ic*32+oc0)*9;
    #pragma unroll
    for(int o=0;o<8;o++){
      #pragma unroll
      for(int pr=0;pr<2;pr++)
        #pragma unroll
        for(int pc=0;pc<2;pc++){
          float s=acc[o][pr*2+pc];
          #pragma unroll
          for(int ky=0;ky<3;ky++)
            #pragma unroll
            for(int kx=0;kx<3;kx++)
              s=fmaf(in[pr+ky][pc+kx], wp[o*9+ky*3+kx], s);
          acc[o][pr*2+pc]=s;
        }
    }
  }
  // write half 1 to buf1 (loads already in flight)
  #pragma unroll
  for(int s=0;s<6;s++)
    if(s<5 || t<16) *(float2*)&t2[1][lofs[s]]=make_float2(c0r[s],c1r[s]);
  __syncthreads();
  // compute half 1
  #pragma unroll 4
  for(int ic=0;ic<8;ic++){
    float in[4][4];
    #pragma unroll
    for(int r=0;r<4;r++){
      float2 a=*(const float2*)&t2[1][ic*360 + base0 + r*20];
      float2 c=*(const float2*)&t2[1][ic*360 + base0 + r*20 + 2];
      in[r][0]=a.x; in[r][1]=a.y; in[r][2]=c.x; in[r][3]=c.y;
    }
    const float* wp = w2t + ((8+ic)*32+oc0)*9;
    #pragma unroll
    for(int o=0;o<8;o++){
      #pragma unroll
      for(int pr=0;pr<2;pr++)
        #pragma unroll
        for(int pc=0;pc<2;pc++){
          float s=acc[o][pr*2+pc];
          #pragma unroll
          for(int ky=0;ky<3;ky++)
            #pragma unroll
            for(int kx=0;kx<3;kx++)
              s=fmaf(in[pr+ky][pc+kx], wp[o*9+ky*3+kx], s);
          acc[o][pr*2+pc]=s;
        }
    }
  }

  const int py=blockIdx.x*8+pyl, px=blockIdx.y*8+pxl;
  double s=0.0, s2=0.0;
  #pragma unroll
  for(int o=0;o<8;o++){
    const int oc=oc0+o;
    float m=fmaxf(fmaxf(acc[o][0],acc[o][1]),fmaxf(acc[o][2],acc[o][3]));
    float hv=m+b2[oc];
    h2[(((size_t)b*32+oc)*64+py)*64+px]=hv;
    s += (double)hv; s2 += (double)hv*(double)hv;
  }
  #pragma unroll
  for(int off=32;off;off>>=1){
    s  += __shfl_xor(s,  off, 64);
    s2 += __shfl_xor(s2, off, 64);
  }
  if(pos==0){
    const int bidx = blockIdx.x*8 + blockIdx.y;
    double* p = pb + (((size_t)b*4+ocg)*64 + bidx)*2;
    p[0]=s; p[1]=s2;
  }
}

// ---------------- K3: groupnorm stats (fused) + apply + 1x1 conv + residual LFQ ----------------
__global__ __launch_bounds__(256) void k_lfq(const float* __restrict__ h2,
    const double* __restrict__ pb, const float* __restrict__ w3, const float* __restrict__ b3,
    float* __restrict__ qout, float* __restrict__ idxout,
    float* __restrict__ avgp, float* __restrict__ ec)
{
  __shared__ __align__(16) float tabL[16*260];
  __shared__ __align__(16) float tabH[16*260];
  __shared__ float smu[4], srs[4];
  const int blk=blockIdx.x;
  const int b=blk>>4;
  const int t=threadIdx.x;
  const int h=(blk&15)*4 + (t>>6);
  const int w=t&63;
  {
    const int wv=t>>6, ln=t&63;
    double s = pb[(((size_t)b*4+wv)*64+ln)*2];
    double s2= pb[(((size_t)b*4+wv)*64+ln)*2+1];
    #pragma unroll
    for(int off=32;off;off>>=1){
      s  += __shfl_xor(s,  off, 64);
      s2 += __shfl_xor(s2, off, 64);
    }
    if(ln==0){
      double mu=s/32768.0;
      double var=s2/32768.0 - mu*mu;
      smu[wv]=(float)mu;
      srs[wv]=(float)(1.0/sqrt(var+1e-5));
    }
  }
  __syncthreads();
  float mu[4], rs[4];
  #pragma unroll
  for(int g=0;g<4;g++){ mu[g]=smu[g]; rs[g]=srs[g]; }
  const float* hp = h2 + (size_t)b*131072 + h*64 + w;
  float z[8];
  #pragma unroll
  for(int d=0;d<8;d++) z[d]=b3[d];
  #pragma unroll
  for(int c=0;c<32;c++){
    float xn=(hp[(size_t)c*4096]-mu[c>>3])*rs[c>>3];
    #pragma unroll
    for(int d=0;d<8;d++) z[d]=fmaf(xn, w3[d*32+c], z[d]);
  }
  float r[8], qsum[8];
  #pragma unroll
  for(int d=0;d<8;d++){ r[d]=z[d]; qsum[d]=0.f; }
  float entk[2], comk[2];
  #pragma unroll
  for(int k=0;k<2;k++){
    int idx=0; float ent=0.f, com=0.f;
    float pb0[8], pb1[8];
    #pragma unroll
    for(int d=0;d<8;d++){
      float rv=r[d];
      bool pos = rv>0.f;
      float sgn = pos?1.f:-1.f;
      idx |= (pos?1:0)<<d;
      float dd=rv-sgn; com=fmaf(dd,dd,com);
      float a=400.f*fabsf(rv);
      float e=__expf(-a);
      float p=1.f/(1.f+e);
      ent += a - p*a - __logf(p);
      float pm=p, pq=1.f-p;
      pb1[d]=pos?pm:pq;
      pb0[d]=pos?pq:pm;
      qsum[d]+=sgn;
      r[d]=rv-sgn;
    }
    float lo[16], hi[16];
    lo[0]=pb0[0]; lo[1]=pb1[0];
    lo[2]=lo[0]*pb1[1]; lo[3]=lo[1]*pb1[1]; lo[0]*=pb0[1]; lo[1]*=pb0[1];
    lo[4]=lo[0]*pb1[2]; lo[5]=lo[1]*pb1[2]; lo[6]=lo[2]*pb1[2]; lo[7]=lo[3]*pb1[2];
    lo[0]*=pb0[2]; lo[1]*=pb0[2]; lo[2]*=pb0[2]; lo[3]*=pb0[2];
    lo[8]=lo[0]*pb1[3]; lo[9]=lo[1]*pb1[3]; lo[10]=lo[2]*pb1[3]; lo[11]=lo[3]*pb1[3];
    lo[12]=lo[4]*pb1[3]; lo[13]=lo[5]*pb1[3]; lo[14]=lo[6]*pb1[3]; lo[15]=lo[7]*pb1[3];
    lo[0]*=pb0[3]; lo[1]*=pb0[3]; lo[2]*=pb0[3]; lo[3]*=pb0[3];
    lo[4]*=pb0[3]; lo[5]*=pb0[3]; lo[6]*=pb0[3]; lo[7]*=pb0[3];
    hi[0]=pb0[4]; hi[1]=pb1[4];
    hi[2]=hi[0]*pb1[5]; hi[3]=hi[1]*pb1[5]; hi[0]*=pb0[5]; hi[1]*=pb0[5];
    hi[4]=hi[0]*pb1[6]; hi[5]=hi[1]*pb1[6]; hi[6]=hi[2]*pb1[6]; hi[7]=hi[3]*pb1[6];
    hi[0]*=pb0[6]; hi[1]*=pb0[6]; hi[2]*=pb0[6]; hi[3]*=pb0[6];
    hi[8]=hi[0]*pb1[7]; hi[9]=hi[1]*pb1[7]; hi[10]=hi[2]*pb1[7]; hi[11]=hi[3]*pb1[7];
    hi[12]=hi[4]*pb1[7]; hi[13]=hi[5]*pb1[7]; hi[14]=hi[6]*pb1[7]; hi[15]=hi[7]*pb1[7];
    hi[0]*=pb0[7]; hi[1]*=pb0[7]; hi[2]*=pb0[7]; hi[3]*=pb0[7];
    hi[4]*=pb0[7]; hi[5]*=pb0[7]; hi[6]*=pb0[7]; hi[7]*=pb0[7];
    #pragma unroll
    for(int m=0;m<16;m++){ tabL[m*260+t]=lo[m]; tabH[m*260+t]=hi[m]; }
    __syncthreads();
    float accp=0.f, accq=0.f;
    const int jl=t&15, jh=t>>4;
    const float* Lp=&tabL[jl*260];
    const float* Hp=&tabH[jh*260];
    #pragma unroll 4
    for(int q4=0;q4<64;q4++){
      float4 L=*(const float4*)&Lp[4*q4];
      float4 H=*(const float4*)&Hp[4*q4];
      accp=fmaf(L.x,H.x,accp); accq=fmaf(L.y,H.y,accq);
      accp=fmaf(L.z,H.z,accp); accq=fmaf(L.w,H.w,accq);
    }
    avgp[((size_t)k*512+blk)*256+t]=accp+accq;
    __syncthreads();
    entk[k]=ent; comk[k]=com;
    idxout[((size_t)(b*64+h)*64+w)*2+k]=(float)idx;
  }
  #pragma unroll
  for(int d=0;d<8;d++)
    qout[(((size_t)b*8+d)*64+h)*64+w]=qsum[d];
  tabL[t]=entk[0]; tabL[256+t]=entk[1]; tabL[512+t]=comk[0]; tabL[768+t]=comk[1];
  __syncthreads();
  for(int st=128;st>0;st>>=1){
    if(t<st){ tabL[t]+=tabL[t+st]; tabL[256+t]+=tabL[256+t+st];
              tabL[512+t]+=tabL[512+t+st]; tabL[768+t]+=tabL[768+t+st]; }
    __syncthreads();
  }
  if(t==0){ ec[blk*4+0]=tabL[0]; ec[blk*4+1]=tabL[256]; ec[blk*4+2]=tabL[512]; ec[blk*4+3]=tabL[768]; }
}

// ---------------- K4: decoder conv d1 (8->32, 3x3, pad1) on 64x64  (+ piggybacked avgp red) ----------------
// 32 designated blocks (x==0, z<4) also reduce avgp -> avgs (stream-ordered after lfq).
__global__ __launch_bounds__(256) void k_dec1(const float* __restrict__ q,
    const float* __restrict__ d1, const float* __restrict__ db1, float* __restrict__ out1,
    const float* __restrict__ avgp, float* __restrict__ avgs)
{
  __shared__ float tile[8*110];
  __shared__ float red[256];
  const int b=blockIdx.z, r0=blockIdx.x*8, c0=blockIdx.y*8;
  const float* qp = q + (size_t)b*8*4096;
  for(int i=threadIdx.x;i<800;i+=256){
    int ic=i/100, rem=i-ic*100, r=rem/10, c=rem-r*10;
    int gr=r0+r-1, gc=c0+c-1;
    float v=0.f;
    if(gr>=0&&gr<64&&gc>=0&&gc<64) v=qp[ic*4096+gr*64+gc];
    tile[ic*110+r*11+c]=v;
  }
  __syncthreads();
  const int ocg=__builtin_amdgcn_readfirstlane((int)(threadIdx.x>>6));
  const int oc0=ocg*8;
  const int l=threadIdx.x&63, ry=l>>3, cx=l&7;
  float acc[8];
  #pragma unroll
  for(int o=0;o<8;o++) acc[o]=db1[oc0+o];
  #pragma unroll 2
  for(int ic=0;ic<8;ic++){
    float v[9];
    #pragma unroll
    for(int ky=0;ky<3;ky++)
      #pragma unroll
      for(int kx=0;kx<3;kx++)
        v[ky*3+kx]=tile[ic*110+(ry+ky)*11+cx+kx];
    #pragma unroll
    for(int o=0;o<8;o++){
      const float* wp=&d1[((oc0+o)*8+ic)*9];
      float s=acc[o];
      #pragma unroll
      for(int kk=0;kk<9;kk++) s=fmaf(v[kk],wp[kk],s);
      acc[o]=s;
    }
  }
  #pragma unroll
  for(int o=0;o<8;o++)
    out1[(((size_t)b*32+oc0+o)*64 + r0+ry)*64 + c0+cx]=acc[o];
  // ---- piggybacked avgp reduction (was k_red; 32 blocks) ----
  if(blockIdx.x==0 && b<4){
    const int rid = b*8 + blockIdx.y;          // 0..31
    const int k=rid>>4, cc0=(rid&15)*16;
    const int col=threadIdx.x&15, rg=threadIdx.x>>4;
    float s=0.f;
    for(int j=0;j<32;j++){
      int blk=rg+16*j;
      s+=avgp[((size_t)k*512+blk)*256+cc0+col];
    }
    red[threadIdx.x]=s; __syncthreads();
    for(int st=128;st>=16;st>>=1){
      if(threadIdx.x<st) red[threadIdx.x]+=red[threadIdx.x+st];
      __syncthreads();
    }
    if(threadIdx.x<16) avgs[k*256+cc0+threadIdx.x]=red[threadIdx.x];
  }
}

// ---------------- K5: upsample2 + conv d2 + gelu  (+ piggybacked aux finalization) ----------------
// Block (0,0,0) also computes the final aux scalar (reads avgs from the k_dec1 dispatch).
__global__ __launch_bounds__(256) void k_dec2(const float* __restrict__ out1,
    const float* __restrict__ wp4d2, const float* __restrict__ db2, float* __restrict__ out2,
    const float* __restrict__ avgs, const float* __restrict__ ec, float* __restrict__ auxout)
{
  __shared__ float tile[32*110];
  __shared__ double redd[256];
  const int b=blockIdx.z, y0=blockIdx.x*16, x0=blockIdx.y*16;
  const int sy0=(y0>>1)-1, sx0=(x0>>1)-1;
  const float* sp = out1 + (size_t)b*32*4096;
  for(int i=threadIdx.x;i<3200;i+=256){
    int ic=i/100, rem=i-ic*100, r=rem/10, c=rem-r*10;
    int gr=sy0+r, gc=sx0+c;
    float v=0.f;
    if(gr>=0&&gr<64&&gc>=0&&gc<64) v=sp[ic*4096+gr*64+gc];
    tile[ic*110+r*11+c]=v;
  }
  __syncthreads();
  const int par=__builtin_amdgcn_readfirstlane((int)(threadIdx.x>>6));
  const int py=par>>1, px=par&1;
  const int l=threadIdx.x&63, ry=l>>3, cx=l&7;
  const int byl=ry+py, bxl=cx+px;
  float acc[16];
  #pragma unroll
  for(int o=0;o<16;o++) acc[o]=db2[o];
  #pragma unroll 2
  for(int ic=0;ic<32;ic++){
    const float* tp=&tile[ic*110 + byl*11 + bxl];
    const float s00=tp[0], s01=tp[1], s10=tp[11], s11=tp[12];
    const float* wq = wp4d2 + (size_t)((par*32+ic)*16)*4;   // 64 uniform floats
    #pragma unroll
    for(int o=0;o<16;o++)
      acc[o]=fmaf(s00,wq[o*4],fmaf(s01,wq[o*4+1],fmaf(s10,wq[o*4+2],fmaf(s11,wq[o*4+3],acc[o]))));
  }
  const int Y=y0+2*ry+py, X=x0+2*cx+px;
  #pragma unroll
  for(int o=0;o<16;o++)
    out2[((size_t)b*16+o)*16384 + (size_t)Y*128 + X] = gelu_exact(acc[o]);
  // ---- piggybacked aux finalization (was k_final; 1 block) ----
  if(blockIdx.x==0 && blockIdx.y==0 && b==0){
    const int t=threadIdx.x;
    double cb=0.0;
    #pragma unroll
    for(int k=0;k<2;k++){
      double ap=(double)avgs[k*256+t]*(1.0/131072.0);
      cb += -(ap*log(ap+1e-10));
    }
    redd[t]=cb; __syncthreads();
    for(int st=128;st>0;st>>=1){ if(t<st) redd[t]+=redd[t+st]; __syncthreads(); }
    double CB=redd[0]; __syncthreads();
    double e=0.0,c=0.0;
    for(int blk=t;blk<512;blk+=256){
      e += (double)ec[blk*4+0]+(double)ec[blk*4+1];
      c += (double)ec[blk*4+2]+(double)ec[blk*4+3];
    }
    redd[t]=e; __syncthreads();
    for(int st=128;st>0;st>>=1){ if(t<st) redd[t]+=redd[t+st]; __syncthreads(); }
    double E=redd[0]; __syncthreads();
    redd[t]=c; __syncthreads();
    for(int st=128;st>0;st>>=1){ if(t<st) redd[t]+=redd[t+st]; __syncthreads(); }
    if(t==0){
      double C=redd[0];
      auxout[0]=(float)(0.1*(E*(1.0/131072.0) - CB) + C*(1.0/1048576.0));
    }
  }
}

// ---------------- K6: upsample2 + conv d3 (16->1,3x3,pad1) + clip, at 256-res ----------------
__global__ __launch_bounds__(256) void k_dec3(const float* __restrict__ out2,
    const float* __restrict__ d3, const float* __restrict__ db3, float* __restrict__ y)
{
  __shared__ float tile[16*342];   // [ic][18][19] src at 128-res
  __shared__ float4 wp4[64];       // [par*16+ic]
  const int b=blockIdx.z, y0=blockIdx.x*32, x0=blockIdx.y*32;
  const int sy0=(y0>>1)-1, sx0=(x0>>1)-1;
  const float* sp = out2 + (size_t)b*16*16384;
  for(int i=threadIdx.x;i<16*324;i+=256){
    int ic=i/324, rem=i-ic*324, r=rem/18, c=rem-r*18;
    int gr=sy0+r, gc=sx0+c;
    float v=0.f;
    if(gr>=0&&gr<128&&gc>=0&&gc<128) v=sp[ic*16384+gr*128+gc];
    tile[ic*342+r*19+c]=v;
  }
  if(threadIdx.x<64){
    int par=threadIdx.x>>4, ic=threadIdx.x&15;
    int py=par>>1, px=par&1;
    const float* wg = d3 + ic*9;
    float a00=0.f,a01=0.f,a10=0.f,a11=0.f;
    #pragma unroll
    for(int ky=0;ky<3;ky++){
      int sy = py ? (ky>>1) : ((ky>0)?1:0);
      #pragma unroll
      for(int kx=0;kx<3;kx++){
        int sx = px ? (kx>>1) : ((kx>0)?1:0);
        float wv=wg[ky*3+kx];
        if(sy==0){ if(sx==0)a00+=wv; else a01+=wv; }
        else     { if(sx==0)a10+=wv; else a11+=wv; }
      }
    }
    wp4[threadIdx.x]=make_float4(a00,a01,a10,a11);
  }
  __syncthreads();
  const float bias=db3[0];
  const int par=__builtin_amdgcn_readfirstlane((int)(threadIdx.x>>6));
  const int py=par>>1, px=par&1;
  const int l=threadIdx.x&63, r0l=l>>4, cl=l&15;
  const int bxl=cl+px;
  float acc[4];
  #pragma unroll
  for(int a=0;a<4;a++) acc[a]=bias;
  #pragma unroll 2
  for(int ic=0;ic<16;ic++){
    const float4 wv=wp4[par*16+ic];
    #pragma unroll
    for(int a=0;a<4;a++){
      const int byl=r0l+4*a+py;
      const float* tp=&tile[ic*342 + byl*19 + bxl];
      acc[a]=fmaf(tp[0],wv.x,fmaf(tp[1],wv.y,fmaf(tp[19],wv.z,fmaf(tp[20],wv.w,acc[a]))));
    }
  }
  #pragma unroll
  for(int a=0;a<4;a++){
    const int yy=2*(r0l+4*a)+py, xx=2*cl+px;
    float v=fminf(fmaxf(acc[a],-1.0f),1.0f);
    y[(size_t)b*65536 + (size_t)(y0+yy)*256 + (x0+xx)] = v;
  }
}

extern "C" void kernel_launch(void* const* d_in, const int* in_sizes, int n_in,
                              void* d_out, int out_size, void* d_ws, size_t ws_size,
                              hipStream_t stream)
{
  const float* x  =(const float*)d_in[0];
  const float* w1 =(const float*)d_in[1];
  const float* b1 =(const float*)d_in[2];
  const float* w2 =(const float*)d_in[3];
  const float* b2 =(const float*)d_in[4];
  const float* w3 =(const float*)d_in[5];
  const float* b3 =(const float*)d_in[6];
  const float* d1 =(const float*)d_in[7];
  const float* db1=(const float*)d_in[8];
  const float* d2 =(const float*)d_in[9];
  const float* db2=(const float*)d_in[10];
  const float* d3 =(const float*)d_in[11];
  const float* db3=(const float*)d_in[12];
  float* out=(float*)d_out;
  float* ws =(float*)d_ws;
  // ws layout (floats):
  // h1[8388608] | h2[4194304] | qb[1048576] | (gap) | avgp[262144] | ec[2048]
  // | wp4d2[8192] | avgs[512]
  // Aliases (stream-order disjoint):
  //   w2t (4608 fl) = head of avgp  (conv1-prep -> conv2, then lfq overwrites avgp)
  //   out1 = h2 (h2 dead after lfq) ; out2 = h1 (h1 dead after conv2)
  // d_out scratch (y region, fully overwritten by dec3):
  //   pb (16384 f64 = 32768 fl) @ out+0  (conv2 -> lfq)
  float* h1   = ws;
  float* h2   = ws + 8388608;
  float* qb   = ws + 12582912;
  float* avgp = ws + 13631744;
  float* ec   = ws + 13893888;
  float* wp4d2= ws + 13895936;
  float* avgs = ws + 13904128;
  float* w2t  = avgp;
  double* pb  = (double*)out;
  float* out1 = h2;
  float* out2 = h1;

  k_conv1<<<dim3(8,8,32),256,0,stream>>>(x,w1,b1,h1,w2,d2,w2t,wp4d2);
  k_conv2<<<dim3(8,8,32),256,0,stream>>>(h1,w2t,b2,h2,pb);
  k_lfq  <<<dim3(512),256,0,stream>>>(h2,pb,w3,b3,qb,out+2097152,avgp,ec);
  k_dec1 <<<dim3(8,8,32),256,0,stream>>>(qb,d1,db1,out1,avgp,avgs);
  k_dec2 <<<dim3(8,8,32),256,0,stream>>>(out1,wp4d2,db2,out2,avgs,ec,out+2359296);
  k_dec3 <<<dim3(8,8,32),256,0,stream>>>(out2,d3,db3,out);
}